// Round 5
// baseline (322.826 us; speedup 1.0000x reference)
//
#include <hip/hip_runtime.h>
#include <hip/hip_cooperative_groups.h>
#include <stdint.h>

namespace cg = cooperative_groups;

#define F8MAX 448.0f
#define QEPS 1e-12f
#define SCL_ONE 0x7F7F7F7F   // E8M0 exponent 127 => 2^0 = 1.0 per byte

typedef float floatx16 __attribute__((ext_vector_type(16)));
typedef int   intx4    __attribute__((ext_vector_type(4)));
typedef int   intx8    __attribute__((ext_vector_type(8)));

// ---- quantize one (128-row panel, 64-col k-tile) block into MX-scrambled layout ----
// Element (r, k): h=k>>5, pc=(k>>4)&1, b=k&15 -> byte = h*4096 + pc*2048 + r*16 + b
__device__ __forceinline__ void quant_tile(const float* __restrict__ in, uint8_t* __restrict__ out,
                                           int tile, float scale, int nkt, int K)
{
    int p  = tile / nkt;
    int kt = tile - p * nkt;
    uint8_t* dst = out + (size_t)tile * 8192;
    #pragma unroll
    for (int i = 0; i < 2; i++) {
        int idx = threadIdx.x + i * 256;       // 0..511
        int h  = idx >> 8;
        int pc = (idx >> 7) & 1;
        int r  = idx & 127;
        const float* src = in + (size_t)(p * 128 + r) * K + kt * 64 + h * 32 + pc * 16;
        float4 f0 = *(const float4*)(src);
        float4 f1 = *(const float4*)(src + 4);
        float4 f2 = *(const float4*)(src + 8);
        float4 f3 = *(const float4*)(src + 12);
        int w0 = 0, w1 = 0, w2 = 0, w3 = 0;
        w0 = __builtin_amdgcn_cvt_pk_fp8_f32(f0.x / scale, f0.y / scale, w0, false);
        w0 = __builtin_amdgcn_cvt_pk_fp8_f32(f0.z / scale, f0.w / scale, w0, true);
        w1 = __builtin_amdgcn_cvt_pk_fp8_f32(f1.x / scale, f1.y / scale, w1, false);
        w1 = __builtin_amdgcn_cvt_pk_fp8_f32(f1.z / scale, f1.w / scale, w1, true);
        w2 = __builtin_amdgcn_cvt_pk_fp8_f32(f2.x / scale, f2.y / scale, w2, false);
        w2 = __builtin_amdgcn_cvt_pk_fp8_f32(f2.z / scale, f2.w / scale, w2, true);
        w3 = __builtin_amdgcn_cvt_pk_fp8_f32(f3.x / scale, f3.y / scale, w3, false);
        w3 = __builtin_amdgcn_cvt_pk_fp8_f32(f3.z / scale, f3.w / scale, w3, true);
        int4 rv; rv.x = w0; rv.y = w1; rv.z = w2; rv.w = w3;
        *(int4*)(dst + (size_t)idx * 16) = rv;
    }
}

// ---------------- fused cooperative: amax(x,w) -> grid.sync -> quantize both ----------------
__global__ __launch_bounds__(256) void fused_amax_quant(
    const float* __restrict__ x, const float* __restrict__ w,
    uint8_t* __restrict__ x8, uint8_t* __restrict__ w8,
    float* __restrict__ px, float* __restrict__ pw, unsigned* __restrict__ hdr,
    int nx4, int nw4, int ntx, int ntw, int nkt, int K)
{
    cg::grid_group grid = cg::this_grid();

    // ---- stage 1: per-block amax partials for x and w ----
    int tid = blockIdx.x * 256 + threadIdx.x;
    int stride = gridDim.x * 256;
    const float4* x4 = (const float4*)x;
    const float4* w4 = (const float4*)w;
    float mx = 0.f, mw = 0.f;
    for (int i = tid; i < nx4; i += stride) {
        float4 v = x4[i];
        mx = fmaxf(mx, fmaxf(fmaxf(fabsf(v.x), fabsf(v.y)), fmaxf(fabsf(v.z), fabsf(v.w))));
    }
    for (int i = tid; i < nw4; i += stride) {
        float4 v = w4[i];
        mw = fmaxf(mw, fmaxf(fmaxf(fabsf(v.x), fabsf(v.y)), fmaxf(fabsf(v.z), fabsf(v.w))));
    }
    #pragma unroll
    for (int off = 32; off; off >>= 1) {
        mx = fmaxf(mx, __shfl_xor(mx, off, 64));
        mw = fmaxf(mw, __shfl_xor(mw, off, 64));
    }
    __shared__ float smx[4], smw[4];
    if ((threadIdx.x & 63) == 0) { smx[threadIdx.x >> 6] = mx; smw[threadIdx.x >> 6] = mw; }
    __syncthreads();
    if (threadIdx.x == 0) {
        px[blockIdx.x] = fmaxf(fmaxf(smx[0], smx[1]), fmaxf(smx[2], smx[3]));
        pw[blockIdx.x] = fmaxf(fmaxf(smw[0], smw[1]), fmaxf(smw[2], smw[3]));
    }

    grid.sync();   // release-acquire: partials visible across XCDs

    // ---- stage 2: every block reduces all partials itself (no 2nd sync needed) ----
    float gx = 0.f, gw = 0.f;
    for (int i = threadIdx.x; i < (int)gridDim.x; i += 256) {
        gx = fmaxf(gx, px[i]);
        gw = fmaxf(gw, pw[i]);
    }
    #pragma unroll
    for (int off = 32; off; off >>= 1) {
        gx = fmaxf(gx, __shfl_xor(gx, off, 64));
        gw = fmaxf(gw, __shfl_xor(gw, off, 64));
    }
    __syncthreads();   // protect smx reuse
    if ((threadIdx.x & 63) == 0) { smx[threadIdx.x >> 6] = gx; smw[threadIdx.x >> 6] = gw; }
    __syncthreads();
    float ax = fmaxf(fmaxf(smx[0], smx[1]), fmaxf(smx[2], smx[3]));
    float aw = fmaxf(fmaxf(smw[0], smw[1]), fmaxf(smw[2], smw[3]));
    if (blockIdx.x == 0 && threadIdx.x == 0) {
        hdr[0] = __float_as_uint(ax);
        hdr[1] = __float_as_uint(aw);
    }
    float sclx = fmaxf(ax, QEPS) / F8MAX;   // true fp32 division (matches ref)
    float sclw = fmaxf(aw, QEPS) / F8MAX;

    // ---- stage 3: quantize; x tiles in reverse order to re-hit L3 lines amax just streamed ----
    for (int t = blockIdx.x; t < ntx; t += gridDim.x)
        quant_tile(x, x8, ntx - 1 - t, sclx, nkt, K);
    for (int t = blockIdx.x; t < ntw; t += gridDim.x)
        quant_tile(w, w8, t, sclw, nkt, K);
}

// ---------------- MX-scaled fp8 GEMM (identity scales), 256^2 tile, 1-barrier/kt ----------------
// C[M,N] = (A8 . B8^T) * s + bias[N]; 8 waves (2M x 4N), BK=64, 3 LDS buffers, prefetch 2 ahead.
__global__ __launch_bounds__(512, 1) void gemm_fp8_mx(
    const uint8_t* __restrict__ A8, const uint8_t* __restrict__ B8,
    float* __restrict__ C, const float* __restrict__ bias,
    const unsigned* __restrict__ hdr, int N, int nkt, int nbn)
{
    __shared__ uint8_t lsA[3 * 16384];
    __shared__ uint8_t lsB[3 * 16384];

    // XCD-chunked bijective swizzle (grid % 8 == 0): each XCD gets a contiguous bm range
    int nwg = gridDim.x;
    int bid = blockIdx.x;
    if ((nwg & 7) == 0) {
        int chunk = nwg >> 3;
        bid = (blockIdx.x & 7) * chunk + (blockIdx.x >> 3);
    }
    int bm = bid / nbn, bn = bid - bm * nbn;

    int t = threadIdx.x;
    int wave = t >> 6, lane = t & 63;
    int wr = wave >> 2, wc = wave & 3;        // 2(M) x 4(N)
    int hl = lane >> 5, l31 = lane & 31;

    // ---- staging chunk map: 32 x 1KB chunks per K-tile; wave v owns chunks v*4+p ----
    const uint8_t* gsrc0; const uint8_t* gsrc1; const uint8_t* gsrc2; const uint8_t* gsrc3;
    uint32_t ld0, ld1, ld2, ld3;
    bool isA = (wave < 4);
    {
        int c0 = wave * 4;
        #pragma unroll
        for (int p = 0; p < 4; p++) {
            int c = c0 + p;
            const uint8_t* g;
            uint32_t l;
            if (c < 16) {
                int h = c >> 3, sub = c & 7;
                g = A8 + (size_t)(bm * 2 + h) * nkt * 8192 + sub * 1024 + lane * 16;
                l = (uint32_t)c * 1024;
            } else {
                int cc = c - 16, h = cc >> 3, sub = cc & 7;
                g = B8 + (size_t)(bn * 2 + h) * nkt * 8192 + sub * 1024 + lane * 16;
                l = (uint32_t)cc * 1024;
            }
            if (p == 0) { gsrc0 = g; ld0 = l; }
            else if (p == 1) { gsrc1 = g; ld1 = l; }
            else if (p == 2) { gsrc2 = g; ld2 = l; }
            else { gsrc3 = g; ld3 = l; }
        }
    }
    uint8_t* lsbase = isA ? lsA : lsB;

#define ISSUE(GP, LO, KT2, B2)                                                   \
    __builtin_amdgcn_global_load_lds(                                            \
        (const __attribute__((address_space(1))) void*)((GP) + (size_t)(KT2) * 8192), \
        (__attribute__((address_space(3))) void*)(lsbase + (B2) * 16384 + (LO)), \
        16, 0, 0)

    // fragment read bases
    const uint8_t* baseA = lsA + wr * 8192 + hl * 4096 + l31 * 16;
    const uint8_t* baseB = lsB + (wc >> 1) * 8192 + hl * 4096 + (wc & 1) * 1024 + l31 * 16;

    floatx16 acc[4][2];
    #pragma unroll
    for (int m = 0; m < 4; m++)
        #pragma unroll
        for (int n = 0; n < 2; n++)
            acc[m][n] = (floatx16)(0.0f);

#define RD8(BASE, OFF) __builtin_shufflevector(                         \
        *(const intx4*)((BASE) + (OFF)),                                \
        *(const intx4*)((BASE) + (OFF) + 2048), 0, 1, 2, 3, 4, 5, 6, 7)

#define MMX(m, n) acc[m][n] = __builtin_amdgcn_mfma_scale_f32_32x32x64_f8f6f4( \
        af[m], bf[n], acc[m][n], 0, 0, 0, SCL_ONE, 0, SCL_ONE)

    // ---- prologue: stage tiles 0 and 1 ----
    ISSUE(gsrc0, ld0, 0, 0); ISSUE(gsrc1, ld1, 0, 0); ISSUE(gsrc2, ld2, 0, 0); ISSUE(gsrc3, ld3, 0, 0);
    ISSUE(gsrc0, ld0, 1, 1); ISSUE(gsrc1, ld1, 1, 1); ISSUE(gsrc2, ld2, 1, 1); ISSUE(gsrc3, ld3, 1, 1);
    asm volatile("s_waitcnt vmcnt(4)" ::: "memory");
    asm volatile("s_barrier" ::: "memory");

    int cur = 0;
    for (int kt = 0; kt < nkt; kt++) {
        bool pf = (kt + 2 < nkt);
        int ib = cur - 1; if (ib < 0) ib += 3;          // (kt+2) % 3
        const uint8_t* cA = baseA + cur * 16384;
        const uint8_t* cB = baseB + cur * 16384;
        intx8 af[4], bf[2];

        if (pf) { ISSUE(gsrc0, ld0, kt + 2, ib); ISSUE(gsrc1, ld1, kt + 2, ib);
                  ISSUE(gsrc2, ld2, kt + 2, ib); ISSUE(gsrc3, ld3, kt + 2, ib); }

        // all operand reads up front; compiler's partial lgkm waits let early MFMAs
        // overlap late ds_read completions (cross-wave overlap via free-running waves)
        af[0] = RD8(cA, 0);    af[1] = RD8(cA, 512);
        bf[0] = RD8(cB, 0);    bf[1] = RD8(cB, 512);
        af[2] = RD8(cA, 1024); af[3] = RD8(cA, 1536);

        __builtin_amdgcn_s_setprio(1);
        MMX(0, 0); MMX(0, 1); MMX(1, 0); MMX(1, 1);
        MMX(2, 0); MMX(2, 1); MMX(3, 0); MMX(3, 1);
        __builtin_amdgcn_s_setprio(0);

        if (kt + 1 < nkt) {
            if (pf) asm volatile("s_waitcnt vmcnt(4)" ::: "memory");
            else    asm volatile("s_waitcnt vmcnt(0)" ::: "memory");
            asm volatile("s_barrier" ::: "memory");   // buffer kt+1 ready for all waves
        }
        cur++; if (cur == 3) cur = 0;
    }

    float sxv = fmaxf(__uint_as_float(hdr[0]), QEPS) / F8MAX;
    float swv = fmaxf(__uint_as_float(hdr[1]), QEPS) / F8MAX;
    float s = sxv * swv;

    // C/D 32x32: col = lane&31, row = (reg&3) + 8*(reg>>2) + 4*(lane>>5)
    #pragma unroll
    for (int m = 0; m < 4; m++) {
        int row0 = bm * 256 + wr * 128 + m * 32 + 4 * hl;
        #pragma unroll
        for (int n = 0; n < 2; n++) {
            int col = bn * 256 + wc * 64 + n * 32 + l31;
            float bv = bias[col];
            #pragma unroll
            for (int reg = 0; reg < 16; reg++) {
                int row = row0 + (reg & 3) + 8 * (reg >> 2);
                __builtin_nontemporal_store(acc[m][n][reg] * s + bv, &C[(size_t)row * N + col]);
            }
        }
    }
#undef ISSUE
#undef RD8
#undef MMX
}

extern "C" void kernel_launch(void* const* d_in, const int* in_sizes, int n_in,
                              void* d_out, int out_size, void* d_ws, size_t ws_size,
                              hipStream_t stream)
{
    const float* x    = (const float*)d_in[0];
    const float* w    = (const float*)d_in[1];
    const float* bias = (const float*)d_in[2];
    float* out = (float*)d_out;

    int N = in_sizes[2];                 // 1024
    int K = in_sizes[1] / N;             // 1024
    int M = in_sizes[0] / K;             // 65536
    int nx = in_sizes[0];
    int nw = in_sizes[1];
    int nkt = K / 64;                    // 16

    uint8_t* ws = (uint8_t*)d_ws;
    unsigned* hdr = (unsigned*)ws;
    float* px = (float*)(ws + 64);                    // 1024 partials (x)
    float* pw = (float*)(ws + 64 + 4096);             // 1024 partials (w)
    uint8_t* w8 = ws + 16384;
    uint8_t* x8 = ws + 16384 + (size_t)N * K;

    int nx4 = nx / 4, nw4 = nw / 4;
    int ntx = (M / 128) * nkt;           // 8192
    int ntw = (N / 128) * nkt;           // 128
    int Kv = K;

    const float* xa = x; const float* wa = w;
    uint8_t* x8a = x8; uint8_t* w8a = w8;
    float* pxa = px; float* pwa = pw; unsigned* hdra = hdr;
    void* args[] = { &xa, &wa, &x8a, &w8a, &pxa, &pwa, &hdra,
                     &nx4, &nw4, &ntx, &ntw, &nkt, &Kv };
    hipLaunchCooperativeKernel((void*)fused_amax_quant, dim3(1024), dim3(256),
                               args, 0, stream);

    int nbm = M / 256, nbn = N / 256;
    gemm_fp8_mx<<<nbm * nbn, 512, 0, stream>>>(x8, w8, out, bias, hdr, N, nkt, nbn);
}

// Round 6
// 233.205 us; speedup vs baseline: 1.3843x; 1.3843x over previous
//
#include <hip/hip_runtime.h>
#include <stdint.h>

#define F8MAX 448.0f
#define QEPS 1e-12f
#define SCL_ONE 0x7F7F7F7F   // E8M0 exponent 127 => 2^0 = 1.0 per byte

typedef float floatx16 __attribute__((ext_vector_type(16)));
typedef int   intx4    __attribute__((ext_vector_type(4)));
typedef int   intx8    __attribute__((ext_vector_type(8)));

// ---------------- pass 1: per-block amax partials ----------------
__global__ void amax_partial(const float* __restrict__ in, int n4, float* __restrict__ partial)
{
    const float4* in4 = (const float4*)in;
    int tid = blockIdx.x * blockDim.x + threadIdx.x;
    int stride = gridDim.x * blockDim.x;
    float m = 0.0f;
    for (int i = tid; i < n4; i += stride) {
        float4 v = in4[i];
        m = fmaxf(m, fmaxf(fmaxf(fabsf(v.x), fabsf(v.y)), fmaxf(fabsf(v.z), fabsf(v.w))));
    }
    #pragma unroll
    for (int off = 32; off > 0; off >>= 1)
        m = fmaxf(m, __shfl_xor(m, off, 64));
    __shared__ float sm[4];
    if ((threadIdx.x & 63) == 0) sm[threadIdx.x >> 6] = m;
    __syncthreads();
    if (threadIdx.x == 0)
        partial[blockIdx.x] = fmaxf(fmaxf(sm[0], sm[1]), fmaxf(sm[2], sm[3]));
}

// ---------------- pass 2: final reduce of both partial arrays ----------------
__global__ void final_reduce(const float* __restrict__ px, int nx,
                             const float* __restrict__ pw, int nw,
                             unsigned* __restrict__ hdr)
{
    float mx = 0.0f, mw = 0.0f;
    for (int i = threadIdx.x; i < nx; i += 256) mx = fmaxf(mx, px[i]);
    for (int i = threadIdx.x; i < nw; i += 256) mw = fmaxf(mw, pw[i]);
    #pragma unroll
    for (int off = 32; off > 0; off >>= 1) {
        mx = fmaxf(mx, __shfl_xor(mx, off, 64));
        mw = fmaxf(mw, __shfl_xor(mw, off, 64));
    }
    __shared__ float sx[4], sw[4];
    if ((threadIdx.x & 63) == 0) { sx[threadIdx.x >> 6] = mx; sw[threadIdx.x >> 6] = mw; }
    __syncthreads();
    if (threadIdx.x == 0) {
        hdr[0] = __float_as_uint(fmaxf(fmaxf(sx[0], sx[1]), fmaxf(sx[2], sx[3])));
        hdr[1] = __float_as_uint(fmaxf(fmaxf(sw[0], sw[1]), fmaxf(sw[2], sw[3])));
    }
}

// ---------------- pass 3: quantize fp32 -> fp8 e4m3 into MX-fragment-scrambled layout ----------
// Per (128-row panel p, 64-col k-tile kt): 8192-byte block. Element (r, k):
//   h = k>>5 (lane-half), pc = (k>>4)&1 (b128 piece), b = k&15
//   byte offset = h*4096 + pc*2048 + r*16 + b
// 32x32x64 f8f6f4 lane (row r=l&31, k=(l>>5)*32+j) reads two b128s at (h=l>>5, pc=0/1, r):
// 16 consecutive lanes read 256B contiguous LDS -> conflict-free.
__global__ void quant_scramble(const float* __restrict__ in, uint8_t* __restrict__ out,
                               const unsigned* __restrict__ hdr, int hidx, int nkt, int K, int rev)
{
    int bid = blockIdx.x;
    if (rev) bid = gridDim.x - 1 - bid;   // back-to-front: re-hit L3 lines amax just streamed
    int p  = bid / nkt;
    int kt = bid - p * nkt;
    float amax = __uint_as_float(hdr[hidx]);
    float scale = fmaxf(amax, QEPS) / F8MAX;   // true fp32 division (matches ref)

    uint8_t* dst = out + (size_t)bid * 8192;

    #pragma unroll
    for (int i = 0; i < 2; i++) {
        int idx = threadIdx.x + i * 256;       // 0..511
        int h  = idx >> 8;
        int pc = (idx >> 7) & 1;
        int r  = idx & 127;
        const float* src = in + (size_t)(p * 128 + r) * K + kt * 64 + h * 32 + pc * 16;
        float4 f0 = *(const float4*)(src);
        float4 f1 = *(const float4*)(src + 4);
        float4 f2 = *(const float4*)(src + 8);
        float4 f3 = *(const float4*)(src + 12);
        int w0 = 0, w1 = 0, w2 = 0, w3 = 0;
        w0 = __builtin_amdgcn_cvt_pk_fp8_f32(f0.x / scale, f0.y / scale, w0, false);
        w0 = __builtin_amdgcn_cvt_pk_fp8_f32(f0.z / scale, f0.w / scale, w0, true);
        w1 = __builtin_amdgcn_cvt_pk_fp8_f32(f1.x / scale, f1.y / scale, w1, false);
        w1 = __builtin_amdgcn_cvt_pk_fp8_f32(f1.z / scale, f1.w / scale, w1, true);
        w2 = __builtin_amdgcn_cvt_pk_fp8_f32(f2.x / scale, f2.y / scale, w2, false);
        w2 = __builtin_amdgcn_cvt_pk_fp8_f32(f2.z / scale, f2.w / scale, w2, true);
        w3 = __builtin_amdgcn_cvt_pk_fp8_f32(f3.x / scale, f3.y / scale, w3, false);
        w3 = __builtin_amdgcn_cvt_pk_fp8_f32(f3.z / scale, f3.w / scale, w3, true);
        int4 rv; rv.x = w0; rv.y = w1; rv.z = w2; rv.w = w3;
        *(int4*)(dst + (size_t)idx * 16) = rv;
    }
}

// ---------------- pass 4: MX-scaled fp8 GEMM (identity scales), 256^2 tile, 1-barrier/kt --------
// C[M,N] = (A8 . B8^T) * s + bias[N]; 8 waves (2M x 4N), BK=64, 3 LDS buffers, prefetch 2 ahead.
// Safety: buffer written at kt is (kt+2)%3 == (kt-1)%3, whose readers all passed the kt-1 end
// barrier (their ds_reads are lgkm-waited before their MFMAs, which precede that barrier);
// writes to it are vmcnt-retired by the end-of-(kt+1) vmcnt(4)+barrier before kt+2 reads.
__global__ __launch_bounds__(512, 1) void gemm_fp8_mx(
    const uint8_t* __restrict__ A8, const uint8_t* __restrict__ B8,
    float* __restrict__ C, const float* __restrict__ bias,
    const unsigned* __restrict__ hdr, int N, int nkt, int nbn)
{
    __shared__ uint8_t lsA[3 * 16384];
    __shared__ uint8_t lsB[3 * 16384];

    // XCD-chunked bijective swizzle (grid % 8 == 0): each XCD gets a contiguous bm range
    int nwg = gridDim.x;
    int bid = blockIdx.x;
    if ((nwg & 7) == 0) {
        int chunk = nwg >> 3;
        bid = (blockIdx.x & 7) * chunk + (blockIdx.x >> 3);
    }
    int bm = bid / nbn, bn = bid - bm * nbn;

    int t = threadIdx.x;
    int wave = t >> 6, lane = t & 63;
    int wr = wave >> 2, wc = wave & 3;        // 2(M) x 4(N)
    int hl = lane >> 5, l31 = lane & 31;

    // ---- staging chunk map: 32 x 1KB chunks per K-tile; wave v owns chunks v*4+p ----
    const uint8_t* gsrc0; const uint8_t* gsrc1; const uint8_t* gsrc2; const uint8_t* gsrc3;
    uint32_t ld0, ld1, ld2, ld3;
    bool isA = (wave < 4);
    {
        int c0 = wave * 4;
        #pragma unroll
        for (int p = 0; p < 4; p++) {
            int c = c0 + p;
            const uint8_t* g;
            uint32_t l;
            if (c < 16) {
                int h = c >> 3, sub = c & 7;
                g = A8 + (size_t)(bm * 2 + h) * nkt * 8192 + sub * 1024 + lane * 16;
                l = (uint32_t)c * 1024;
            } else {
                int cc = c - 16, h = cc >> 3, sub = cc & 7;
                g = B8 + (size_t)(bn * 2 + h) * nkt * 8192 + sub * 1024 + lane * 16;
                l = (uint32_t)cc * 1024;
            }
            if (p == 0) { gsrc0 = g; ld0 = l; }
            else if (p == 1) { gsrc1 = g; ld1 = l; }
            else if (p == 2) { gsrc2 = g; ld2 = l; }
            else { gsrc3 = g; ld3 = l; }
        }
    }
    uint8_t* lsbase = isA ? lsA : lsB;

#define ISSUE(GP, LO, KT2, B2)                                                   \
    __builtin_amdgcn_global_load_lds(                                            \
        (const __attribute__((address_space(1))) void*)((GP) + (size_t)(KT2) * 8192), \
        (__attribute__((address_space(3))) void*)(lsbase + (B2) * 16384 + (LO)), \
        16, 0, 0)

    // fragment read bases
    const uint8_t* baseA = lsA + wr * 8192 + hl * 4096 + l31 * 16;
    const uint8_t* baseB = lsB + (wc >> 1) * 8192 + hl * 4096 + (wc & 1) * 1024 + l31 * 16;

    floatx16 acc[4][2];
    #pragma unroll
    for (int m = 0; m < 4; m++)
        #pragma unroll
        for (int n = 0; n < 2; n++)
            acc[m][n] = (floatx16)(0.0f);

#define RD8(BASE, OFF) __builtin_shufflevector(                         \
        *(const intx4*)((BASE) + (OFF)),                                \
        *(const intx4*)((BASE) + (OFF) + 2048), 0, 1, 2, 3, 4, 5, 6, 7)

#define MMX(m, n) acc[m][n] = __builtin_amdgcn_mfma_scale_f32_32x32x64_f8f6f4( \
        af[m], bf[n], acc[m][n], 0, 0, 0, SCL_ONE, 0, SCL_ONE)

    // ---- prologue: stage tiles 0 and 1 ----
    ISSUE(gsrc0, ld0, 0, 0); ISSUE(gsrc1, ld1, 0, 0); ISSUE(gsrc2, ld2, 0, 0); ISSUE(gsrc3, ld3, 0, 0);
    ISSUE(gsrc0, ld0, 1, 1); ISSUE(gsrc1, ld1, 1, 1); ISSUE(gsrc2, ld2, 1, 1); ISSUE(gsrc3, ld3, 1, 1);
    asm volatile("s_waitcnt vmcnt(4)" ::: "memory");
    asm volatile("s_barrier" ::: "memory");

    int cur = 0;
    for (int kt = 0; kt < nkt; kt++) {
        bool pf = (kt + 2 < nkt);
        int ib = cur - 1; if (ib < 0) ib += 3;          // (kt+2) % 3
        const uint8_t* cA = baseA + cur * 16384;
        const uint8_t* cB = baseB + cur * 16384;
        intx8 af[4], bf[2];

        if (pf) { ISSUE(gsrc0, ld0, kt + 2, ib); ISSUE(gsrc1, ld1, kt + 2, ib);
                  ISSUE(gsrc2, ld2, kt + 2, ib); ISSUE(gsrc3, ld3, kt + 2, ib); }

        // all operand reads up front; compiler's partial lgkm waits let early MFMAs
        // overlap late ds_read completions (cross-wave overlap via free-running waves)
        af[0] = RD8(cA, 0);    af[1] = RD8(cA, 512);
        bf[0] = RD8(cB, 0);    bf[1] = RD8(cB, 512);
        af[2] = RD8(cA, 1024); af[3] = RD8(cA, 1536);

        __builtin_amdgcn_s_setprio(1);
        MMX(0, 0); MMX(0, 1); MMX(1, 0); MMX(1, 1);
        MMX(2, 0); MMX(2, 1); MMX(3, 0); MMX(3, 1);
        __builtin_amdgcn_s_setprio(0);

        if (kt + 1 < nkt) {
            if (pf) asm volatile("s_waitcnt vmcnt(4)" ::: "memory");
            else    asm volatile("s_waitcnt vmcnt(0)" ::: "memory");
            asm volatile("s_barrier" ::: "memory");   // buffer kt+1 ready for all waves
        }
        cur++; if (cur == 3) cur = 0;
    }

    float sxv = fmaxf(__uint_as_float(hdr[0]), QEPS) / F8MAX;
    float swv = fmaxf(__uint_as_float(hdr[1]), QEPS) / F8MAX;
    float s = sxv * swv;

    // C/D 32x32: col = lane&31, row = (reg&3) + 8*(reg>>2) + 4*(lane>>5)
    #pragma unroll
    for (int m = 0; m < 4; m++) {
        int row0 = bm * 256 + wr * 128 + m * 32 + 4 * hl;
        #pragma unroll
        for (int n = 0; n < 2; n++) {
            int col = bn * 256 + wc * 64 + n * 32 + l31;
            float bv = bias[col];
            #pragma unroll
            for (int reg = 0; reg < 16; reg++) {
                int row = row0 + (reg & 3) + 8 * (reg >> 2);
                __builtin_nontemporal_store(acc[m][n][reg] * s + bv, &C[(size_t)row * N + col]);
            }
        }
    }
#undef ISSUE
#undef RD8
#undef MMX
}

extern "C" void kernel_launch(void* const* d_in, const int* in_sizes, int n_in,
                              void* d_out, int out_size, void* d_ws, size_t ws_size,
                              hipStream_t stream)
{
    const float* x    = (const float*)d_in[0];
    const float* w    = (const float*)d_in[1];
    const float* bias = (const float*)d_in[2];
    float* out = (float*)d_out;

    int N = in_sizes[2];                 // 1024
    int K = in_sizes[1] / N;             // 1024
    int M = in_sizes[0] / K;             // 65536
    int nx = in_sizes[0];
    int nw = in_sizes[1];
    int nkt = K / 64;                    // 16

    uint8_t* ws = (uint8_t*)d_ws;
    unsigned* hdr = (unsigned*)ws;
    float* px = (float*)(ws + 64);                    // 4096 partials (x)
    float* pw = (float*)(ws + 64 + 16384);            // 256 partials (w)
    uint8_t* w8 = ws + 65536;
    uint8_t* x8 = ws + 65536 + (size_t)N * K;

    const int AX_BLOCKS = 4096;          // high TLP: the amax pass is latency-bound otherwise
    const int AW_BLOCKS = 256;

    amax_partial<<<AX_BLOCKS, 256, 0, stream>>>(x, nx / 4, px);
    amax_partial<<<AW_BLOCKS, 256, 0, stream>>>(w, nw / 4, pw);
    final_reduce<<<1, 256, 0, stream>>>(px, AX_BLOCKS, pw, AW_BLOCKS, hdr);

    quant_scramble<<<(N / 128) * nkt, 256, 0, stream>>>(w, w8, hdr, 1, nkt, K, 0);
    quant_scramble<<<(M / 128) * nkt, 256, 0, stream>>>(x, x8, hdr, 0, nkt, K, 1);

    int nbm = M / 256, nbn = N / 256;
    gemm_fp8_mx<<<nbm * nbn, 512, 0, stream>>>(x8, w8, out, bias, hdr, N, nkt, nbn);
}

// Round 7
// 219.807 us; speedup vs baseline: 1.4687x; 1.0610x over previous
//
#include <hip/hip_runtime.h>
#include <stdint.h>

#define F8MAX 448.0f
#define QEPS 1e-12f
#define SCL_ONE 0x7F7F7F7F   // E8M0 exponent 127 => 2^0 = 1.0 per byte
#define AXB 4096             // amax partial blocks

typedef float floatx16 __attribute__((ext_vector_type(16)));
typedef int   intx4    __attribute__((ext_vector_type(4)));
typedef int   intx8    __attribute__((ext_vector_type(8)));

// ---------------- pass 1: dual per-block amax partials (x and w in one kernel) ----------------
__global__ __launch_bounds__(256) void amax_partial_xw(
    const float* __restrict__ x, int nx4,
    const float* __restrict__ w, int nw4,
    float* __restrict__ px, float* __restrict__ pw)
{
    const float4* x4 = (const float4*)x;
    const float4* w4 = (const float4*)w;
    int tid = blockIdx.x * 256 + threadIdx.x;
    int stride = gridDim.x * 256;
    float mx = 0.f, mw = 0.f;
    for (int i = tid; i < nx4; i += stride) {
        float4 v = x4[i];
        mx = fmaxf(mx, fmaxf(fmaxf(fabsf(v.x), fabsf(v.y)), fmaxf(fabsf(v.z), fabsf(v.w))));
    }
    for (int i = tid; i < nw4; i += stride) {
        float4 v = w4[i];
        mw = fmaxf(mw, fmaxf(fmaxf(fabsf(v.x), fabsf(v.y)), fmaxf(fabsf(v.z), fabsf(v.w))));
    }
    #pragma unroll
    for (int off = 32; off > 0; off >>= 1) {
        mx = fmaxf(mx, __shfl_xor(mx, off, 64));
        mw = fmaxf(mw, __shfl_xor(mw, off, 64));
    }
    __shared__ float smx[4], smw[4];
    if ((threadIdx.x & 63) == 0) { smx[threadIdx.x >> 6] = mx; smw[threadIdx.x >> 6] = mw; }
    __syncthreads();
    if (threadIdx.x == 0) {
        px[blockIdx.x] = fmaxf(fmaxf(smx[0], smx[1]), fmaxf(smx[2], smx[3]));
        pw[blockIdx.x] = fmaxf(fmaxf(smw[0], smw[1]), fmaxf(smw[2], smw[3]));
    }
}

// ---- quantize one (128-row panel, 64-col k-tile) into MX-fragment-scrambled layout ----
// Element (r, k): h=k>>5, pc=(k>>4)&1, b=k&15 -> byte = h*4096 + pc*2048 + r*16 + b
// 32x32x64 f8f6f4 lane (row r=l&31, k=(l>>5)*32+j) reads two b128s at (h=l>>5, pc=0/1, r):
// 16 consecutive lanes read 256B contiguous LDS -> conflict-free.
__device__ __forceinline__ void quant_tile(const float* __restrict__ in, uint8_t* __restrict__ out,
                                           int tile, float rs, int nkt, int K)
{
    int p  = tile / nkt;
    int kt = tile - p * nkt;
    uint8_t* dst = out + (size_t)tile * 8192;
    #pragma unroll
    for (int i = 0; i < 2; i++) {
        int idx = threadIdx.x + i * 256;       // 0..511
        int h  = idx >> 8;
        int pc = (idx >> 7) & 1;
        int r  = idx & 127;
        const float* src = in + (size_t)(p * 128 + r) * K + kt * 64 + h * 32 + pc * 16;
        float4 f0 = *(const float4*)(src);
        float4 f1 = *(const float4*)(src + 4);
        float4 f2 = *(const float4*)(src + 8);
        float4 f3 = *(const float4*)(src + 12);
        int w0 = 0, w1 = 0, w2 = 0, w3 = 0;
        w0 = __builtin_amdgcn_cvt_pk_fp8_f32(f0.x * rs, f0.y * rs, w0, false);
        w0 = __builtin_amdgcn_cvt_pk_fp8_f32(f0.z * rs, f0.w * rs, w0, true);
        w1 = __builtin_amdgcn_cvt_pk_fp8_f32(f1.x * rs, f1.y * rs, w1, false);
        w1 = __builtin_amdgcn_cvt_pk_fp8_f32(f1.z * rs, f1.w * rs, w1, true);
        w2 = __builtin_amdgcn_cvt_pk_fp8_f32(f2.x * rs, f2.y * rs, w2, false);
        w2 = __builtin_amdgcn_cvt_pk_fp8_f32(f2.z * rs, f2.w * rs, w2, true);
        w3 = __builtin_amdgcn_cvt_pk_fp8_f32(f3.x * rs, f3.y * rs, w3, false);
        w3 = __builtin_amdgcn_cvt_pk_fp8_f32(f3.z * rs, f3.w * rs, w3, true);
        int4 rv; rv.x = w0; rv.y = w1; rv.z = w2; rv.w = w3;
        *(int4*)(dst + (size_t)idx * 16) = rv;
    }
}

// ---------------- pass 2: fused quant (w: blocks 0..127, x: rest, reverse order) ----------------
// Each block redundantly reduces the 4096-entry partial array (deterministic -> identical scale).
__global__ __launch_bounds__(256) void quant_fused(
    const float* __restrict__ x, const float* __restrict__ w,
    uint8_t* __restrict__ x8, uint8_t* __restrict__ w8,
    const float* __restrict__ px, const float* __restrict__ pw,
    unsigned* __restrict__ hdr, int ntx, int nkt, int K)
{
    int bid = blockIdx.x;
    bool isw = (bid < 128);
    const float* par = isw ? pw : px;

    float m = 0.f;
    for (int i = threadIdx.x; i < AXB; i += 256) m = fmaxf(m, par[i]);
    #pragma unroll
    for (int off = 32; off > 0; off >>= 1) m = fmaxf(m, __shfl_xor(m, off, 64));
    __shared__ float red[4];
    if ((threadIdx.x & 63) == 0) red[threadIdx.x >> 6] = m;
    __syncthreads();
    float amax = fmaxf(fmaxf(red[0], red[1]), fmaxf(red[2], red[3]));

    float scale = fmaxf(amax, QEPS) / F8MAX;   // exactly the reference's rounded scale
    float rs = 1.0f / scale;                   // reciprocal-multiply (see analysis)

    if (threadIdx.x == 0) {
        if (bid == 0)   hdr[1] = __float_as_uint(amax);   // amax_w for gemm epilogue
        if (bid == 128) hdr[0] = __float_as_uint(amax);   // amax_x
    }

    if (isw) quant_tile(w, w8, bid, rs, nkt, K);
    else     quant_tile(x, x8, ntx - 1 - (bid - 128), rs, nkt, K);  // back-to-front: L3 reuse
}

// ---------------- pass 3: MX-scaled fp8 GEMM (identity scales), 256^2 tile, 1-barrier/kt -------
// C[M,N] = (A8 . B8^T) * s + bias[N]; 8 waves (2M x 4N), BK=64, 3 LDS buffers, prefetch 2 ahead.
// Safety: buffer written at kt is (kt+2)%3 == (kt-1)%3, whose readers all passed the kt-1 end
// barrier; writes to it are vmcnt-retired by the end-of-(kt+1) vmcnt(4)+barrier before kt+2 reads.
__global__ __launch_bounds__(512, 1) void gemm_fp8_mx(
    const uint8_t* __restrict__ A8, const uint8_t* __restrict__ B8,
    float* __restrict__ C, const float* __restrict__ bias,
    const unsigned* __restrict__ hdr, int N, int nkt, int nbn)
{
    __shared__ uint8_t lsA[3 * 16384];
    __shared__ uint8_t lsB[3 * 16384];

    // XCD-chunked bijective swizzle (grid % 8 == 0): each XCD gets a contiguous bm range
    int nwg = gridDim.x;
    int bid = blockIdx.x;
    if ((nwg & 7) == 0) {
        int chunk = nwg >> 3;
        bid = (blockIdx.x & 7) * chunk + (blockIdx.x >> 3);
    }
    int bm = bid / nbn, bn = bid - bm * nbn;

    int t = threadIdx.x;
    int wave = t >> 6, lane = t & 63;
    int wr = wave >> 2, wc = wave & 3;        // 2(M) x 4(N)
    int hl = lane >> 5, l31 = lane & 31;

    // ---- staging chunk map: 32 x 1KB chunks per K-tile; wave v owns chunks v*4+p ----
    const uint8_t* gsrc0; const uint8_t* gsrc1; const uint8_t* gsrc2; const uint8_t* gsrc3;
    uint32_t ld0, ld1, ld2, ld3;
    bool isA = (wave < 4);
    {
        int c0 = wave * 4;
        #pragma unroll
        for (int p = 0; p < 4; p++) {
            int c = c0 + p;
            const uint8_t* g;
            uint32_t l;
            if (c < 16) {
                int h = c >> 3, sub = c & 7;
                g = A8 + (size_t)(bm * 2 + h) * nkt * 8192 + sub * 1024 + lane * 16;
                l = (uint32_t)c * 1024;
            } else {
                int cc = c - 16, h = cc >> 3, sub = cc & 7;
                g = B8 + (size_t)(bn * 2 + h) * nkt * 8192 + sub * 1024 + lane * 16;
                l = (uint32_t)cc * 1024;
            }
            if (p == 0) { gsrc0 = g; ld0 = l; }
            else if (p == 1) { gsrc1 = g; ld1 = l; }
            else if (p == 2) { gsrc2 = g; ld2 = l; }
            else { gsrc3 = g; ld3 = l; }
        }
    }
    uint8_t* lsbase = isA ? lsA : lsB;

#define ISSUE(GP, LO, KT2, B2)                                                   \
    __builtin_amdgcn_global_load_lds(                                            \
        (const __attribute__((address_space(1))) void*)((GP) + (size_t)(KT2) * 8192), \
        (__attribute__((address_space(3))) void*)(lsbase + (B2) * 16384 + (LO)), \
        16, 0, 0)

    // fragment read bases
    const uint8_t* baseA = lsA + wr * 8192 + hl * 4096 + l31 * 16;
    const uint8_t* baseB = lsB + (wc >> 1) * 8192 + hl * 4096 + (wc & 1) * 1024 + l31 * 16;

    floatx16 acc[4][2];
    #pragma unroll
    for (int m = 0; m < 4; m++)
        #pragma unroll
        for (int n = 0; n < 2; n++)
            acc[m][n] = (floatx16)(0.0f);

#define RD8(BASE, OFF) __builtin_shufflevector(                         \
        *(const intx4*)((BASE) + (OFF)),                                \
        *(const intx4*)((BASE) + (OFF) + 2048), 0, 1, 2, 3, 4, 5, 6, 7)

#define MMX(m, n) acc[m][n] = __builtin_amdgcn_mfma_scale_f32_32x32x64_f8f6f4( \
        af[m], bf[n], acc[m][n], 0, 0, 0, SCL_ONE, 0, SCL_ONE)

    // ---- prologue: stage tiles 0 and 1 ----
    ISSUE(gsrc0, ld0, 0, 0); ISSUE(gsrc1, ld1, 0, 0); ISSUE(gsrc2, ld2, 0, 0); ISSUE(gsrc3, ld3, 0, 0);
    ISSUE(gsrc0, ld0, 1, 1); ISSUE(gsrc1, ld1, 1, 1); ISSUE(gsrc2, ld2, 1, 1); ISSUE(gsrc3, ld3, 1, 1);
    asm volatile("s_waitcnt vmcnt(4)" ::: "memory");
    asm volatile("s_barrier" ::: "memory");

    int cur = 0;
    for (int kt = 0; kt < nkt; kt++) {
        bool pf = (kt + 2 < nkt);
        int ib = cur - 1; if (ib < 0) ib += 3;          // (kt+2) % 3
        const uint8_t* cA = baseA + cur * 16384;
        const uint8_t* cB = baseB + cur * 16384;
        intx8 af[4], bf[2];

        if (pf) { ISSUE(gsrc0, ld0, kt + 2, ib); ISSUE(gsrc1, ld1, kt + 2, ib);
                  ISSUE(gsrc2, ld2, kt + 2, ib); ISSUE(gsrc3, ld3, kt + 2, ib); }

        // all operand reads up front; compiler's partial lgkm waits let early MFMAs
        // overlap late ds_read completions (cross-wave overlap via free-running waves)
        af[0] = RD8(cA, 0);    af[1] = RD8(cA, 512);
        bf[0] = RD8(cB, 0);    bf[1] = RD8(cB, 512);
        af[2] = RD8(cA, 1024); af[3] = RD8(cA, 1536);

        __builtin_amdgcn_s_setprio(1);
        MMX(0, 0); MMX(0, 1); MMX(1, 0); MMX(1, 1);
        MMX(2, 0); MMX(2, 1); MMX(3, 0); MMX(3, 1);
        __builtin_amdgcn_s_setprio(0);

        if (kt + 1 < nkt) {
            if (pf) asm volatile("s_waitcnt vmcnt(4)" ::: "memory");
            else    asm volatile("s_waitcnt vmcnt(0)" ::: "memory");
            asm volatile("s_barrier" ::: "memory");   // buffer kt+1 ready for all waves
        }
        cur++; if (cur == 3) cur = 0;
    }

    float sxv = fmaxf(__uint_as_float(hdr[0]), QEPS) / F8MAX;
    float swv = fmaxf(__uint_as_float(hdr[1]), QEPS) / F8MAX;
    float s = sxv * swv;

    // C/D 32x32: col = lane&31, row = (reg&3) + 8*(reg>>2) + 4*(lane>>5)
    #pragma unroll
    for (int m = 0; m < 4; m++) {
        int row0 = bm * 256 + wr * 128 + m * 32 + 4 * hl;
        #pragma unroll
        for (int n = 0; n < 2; n++) {
            int col = bn * 256 + wc * 64 + n * 32 + l31;
            float bv = bias[col];
            #pragma unroll
            for (int reg = 0; reg < 16; reg++) {
                int row = row0 + (reg & 3) + 8 * (reg >> 2);
                __builtin_nontemporal_store(acc[m][n][reg] * s + bv, &C[(size_t)row * N + col]);
            }
        }
    }
#undef ISSUE
#undef RD8
#undef MMX
}

extern "C" void kernel_launch(void* const* d_in, const int* in_sizes, int n_in,
                              void* d_out, int out_size, void* d_ws, size_t ws_size,
                              hipStream_t stream)
{
    const float* x    = (const float*)d_in[0];
    const float* w    = (const float*)d_in[1];
    const float* bias = (const float*)d_in[2];
    float* out = (float*)d_out;

    int N = in_sizes[2];                 // 1024
    int K = in_sizes[1] / N;             // 1024
    int M = in_sizes[0] / K;             // 65536
    int nx = in_sizes[0];
    int nw = in_sizes[1];
    int nkt = K / 64;                    // 16

    uint8_t* ws = (uint8_t*)d_ws;
    unsigned* hdr = (unsigned*)ws;                    // [0]=amax_x bits, [1]=amax_w bits
    float* px = (float*)(ws + 64);                    // 4096 partials (x)
    float* pw = (float*)(ws + 64 + 16384);            // 4096 partials (w)
    uint8_t* w8 = ws + 65536;
    uint8_t* x8 = ws + 65536 + (size_t)N * K;

    int ntx = (M / 128) * nkt;           // 8192
    int ntw = (N / 128) * nkt;           // 128

    amax_partial_xw<<<AXB, 256, 0, stream>>>(x, nx / 4, w, nw / 4, px, pw);
    quant_fused<<<ntw + ntx, 256, 0, stream>>>(x, w, x8, w8, px, pw, hdr, ntx, nkt, K);

    int nbm = M / 256, nbn = N / 256;
    gemm_fp8_mx<<<nbm * nbn, 512, 0, stream>>>(x8, w8, out, bias, hdr, N, nkt, nbn);
}

// Round 8
// 219.172 us; speedup vs baseline: 1.4729x; 1.0029x over previous
//
#include <hip/hip_runtime.h>
#include <stdint.h>

#define F8MAX 448.0f
#define QEPS 1e-12f
#define SCL_ONE 0x7F7F7F7F   // E8M0 exponent 127 => 2^0 = 1.0 per byte
#define AXB 4096             // amax partial blocks

typedef float floatx16 __attribute__((ext_vector_type(16)));
typedef int   intx4    __attribute__((ext_vector_type(4)));
typedef int   intx8    __attribute__((ext_vector_type(8)));

// ---------------- pass 1: dual per-block amax partials (x and w in one kernel) ----------------
__global__ __launch_bounds__(256) void amax_partial_xw(
    const float* __restrict__ x, int nx4,
    const float* __restrict__ w, int nw4,
    float* __restrict__ px, float* __restrict__ pw)
{
    const float4* x4 = (const float4*)x;
    const float4* w4 = (const float4*)w;
    int tid = blockIdx.x * 256 + threadIdx.x;
    int stride = gridDim.x * 256;
    float mx = 0.f, mw = 0.f;
    for (int i = tid; i < nx4; i += stride) {
        float4 v = x4[i];
        mx = fmaxf(mx, fmaxf(fmaxf(fabsf(v.x), fabsf(v.y)), fmaxf(fabsf(v.z), fabsf(v.w))));
    }
    for (int i = tid; i < nw4; i += stride) {
        float4 v = w4[i];
        mw = fmaxf(mw, fmaxf(fmaxf(fabsf(v.x), fabsf(v.y)), fmaxf(fabsf(v.z), fabsf(v.w))));
    }
    #pragma unroll
    for (int off = 32; off > 0; off >>= 1) {
        mx = fmaxf(mx, __shfl_xor(mx, off, 64));
        mw = fmaxf(mw, __shfl_xor(mw, off, 64));
    }
    __shared__ float smx[4], smw[4];
    if ((threadIdx.x & 63) == 0) { smx[threadIdx.x >> 6] = mx; smw[threadIdx.x >> 6] = mw; }
    __syncthreads();
    if (threadIdx.x == 0) {
        px[blockIdx.x] = fmaxf(fmaxf(smx[0], smx[1]), fmaxf(smx[2], smx[3]));
        pw[blockIdx.x] = fmaxf(fmaxf(smw[0], smw[1]), fmaxf(smw[2], smw[3]));
    }
}

// ---------------- pass 2: coalesced LDS-transposing quant into MX-scrambled layout -------------
// One block = one half-panel (64 rows x K floats). Phase A reads full rows coalesced
// (1KB-contiguous per wave-instr), converts, scatters 4B words into a swizzled 64KB LDS
// image of the scrambled layout. Phase B copies 64 x 1KB chunks out, wave-contiguous.
// Output layout identical to before: tile(p,kt) byte = h*4096 + pc*2048 + r*16 + (k&15),
// h=(k>>5)&1, pc=(k>>4)&1. LDS image: [16 kt][4 hpc][64 r][16B], XOR-swizzled on byte
// bits 4..6 with key = ((kt&1)<<2)|hpc (equal to writer's (lane>>2)&7 -> conflict-free).
__global__ __launch_bounds__(256) void quant_fused(
    const float* __restrict__ x, const float* __restrict__ w,
    uint8_t* __restrict__ x8, uint8_t* __restrict__ w8,
    const float* __restrict__ px, const float* __restrict__ pw,
    unsigned* __restrict__ hdr, int nhx, int nkt, int K)
{
    __shared__ uint8_t lds[65536];

    int bid = blockIdx.x;
    bool isw = (bid < 16);                 // w: 16 half-panels (N=1024)
    const float* par = isw ? pw : px;

    // redundant reduce of the 4096-entry partial array (deterministic -> identical everywhere)
    float m = 0.f;
    for (int i = threadIdx.x; i < AXB; i += 256) m = fmaxf(m, par[i]);
    #pragma unroll
    for (int off = 32; off > 0; off >>= 1) m = fmaxf(m, __shfl_xor(m, off, 64));
    __shared__ float red[4];
    if ((threadIdx.x & 63) == 0) red[threadIdx.x >> 6] = m;
    __syncthreads();
    float amax = fmaxf(fmaxf(red[0], red[1]), fmaxf(red[2], red[3]));

    float scale = fmaxf(amax, QEPS) / F8MAX;   // exactly the reference's scale
    float rs = 1.0f / scale;                   // reciprocal-multiply

    if (threadIdx.x == 0) {
        if (bid == 0)  hdr[1] = __float_as_uint(amax);   // amax_w for gemm epilogue
        if (bid == 16) hdr[0] = __float_as_uint(amax);   // amax_x
    }

    int hp = isw ? bid : (nhx - 1 - (bid - 16));   // x back-to-front: L3 reuse after amax
    const float* src = isw ? w : x;
    uint8_t* dst8 = isw ? w8 : x8;
    int p = hp >> 1, half = hp & 1;

    int wave = threadIdx.x >> 6, lane = threadIdx.x & 63;
    int K4 = K >> 2;

    // ---- phase A: rows -> LDS ----
    const float4* s4 = (const float4*)src + (size_t)(p * 128 + half * 64) * K4;
    uint32_t key = (lane >> 2) & 7;
    uint32_t lbase = ((uint32_t)(lane >> 4) * 4096) + (((lane >> 2) & 3) * 1024) + ((lane & 3) * 4);
    for (int rr = 0; rr < 16; rr++) {
        int r = rr * 4 + wave;
        const float4* rowp = s4 + (size_t)r * K4;
        #pragma unroll
        for (int j = 0; j < 4; j++) {
            float4 f = rowp[j * 64 + lane];    // 1KB contiguous per wave-instr
            int wd = 0;
            wd = __builtin_amdgcn_cvt_pk_fp8_f32(f.x * rs, f.y * rs, wd, false);
            wd = __builtin_amdgcn_cvt_pk_fp8_f32(f.z * rs, f.w * rs, wd, true);
            uint32_t a = (uint32_t)j * 16384 + lbase + (uint32_t)r * 16;
            a ^= (key << 4);
            *(int*)(lds + a) = wd;
        }
    }
    __syncthreads();

    // ---- phase B: LDS -> global, 64 x 1KB chunks, wave-contiguous ----
    uint8_t* outb = dst8 + (size_t)(p * nkt) * 8192 + half * 1024;
    for (int i = 0; i < 16; i++) {
        int c = i * 4 + wave;                  // chunk 0..63
        int kt = c >> 2, hpc = c & 3;
        uint32_t k2 = (uint32_t)(((kt & 1) << 2) | hpc);
        uint32_t a = (uint32_t)c * 1024 + (((uint32_t)lane * 16) ^ (k2 << 4));
        int4 v = *(const int4*)(lds + a);
        *(int4*)(outb + (size_t)kt * 8192 + hpc * 2048 + lane * 16) = v;
    }
}

// ---------------- pass 3: MX-scaled fp8 GEMM (identity scales), 256^2 tile, 1-barrier/kt -------
// C[M,N] = (A8 . B8^T) * s + bias[N]; 8 waves (2M x 4N), BK=64, 3 LDS buffers, prefetch 2 ahead.
// Safety: buffer written at kt is (kt+2)%3 == (kt-1)%3, whose readers all passed the kt-1 end
// barrier; writes to it are vmcnt-retired by the end-of-(kt+1) vmcnt(4)+barrier before kt+2 reads.
__global__ __launch_bounds__(512, 1) void gemm_fp8_mx(
    const uint8_t* __restrict__ A8, const uint8_t* __restrict__ B8,
    float* __restrict__ C, const float* __restrict__ bias,
    const unsigned* __restrict__ hdr, int N, int nkt, int nbn)
{
    __shared__ uint8_t lsA[3 * 16384];
    __shared__ uint8_t lsB[3 * 16384];

    // XCD-chunked bijective swizzle (grid % 8 == 0): each XCD gets a contiguous bm range
    int nwg = gridDim.x;
    int bid = blockIdx.x;
    if ((nwg & 7) == 0) {
        int chunk = nwg >> 3;
        bid = (blockIdx.x & 7) * chunk + (blockIdx.x >> 3);
    }
    int bm = bid / nbn, bn = bid - bm * nbn;

    int t = threadIdx.x;
    int wave = t >> 6, lane = t & 63;
    int wr = wave >> 2, wc = wave & 3;        // 2(M) x 4(N)
    int hl = lane >> 5, l31 = lane & 31;

    // ---- staging chunk map: 32 x 1KB chunks per K-tile; wave v owns chunks v*4+p ----
    const uint8_t* gsrc0; const uint8_t* gsrc1; const uint8_t* gsrc2; const uint8_t* gsrc3;
    uint32_t ld0, ld1, ld2, ld3;
    bool isA = (wave < 4);
    {
        int c0 = wave * 4;
        #pragma unroll
        for (int p = 0; p < 4; p++) {
            int c = c0 + p;
            const uint8_t* g;
            uint32_t l;
            if (c < 16) {
                int h = c >> 3, sub = c & 7;
                g = A8 + (size_t)(bm * 2 + h) * nkt * 8192 + sub * 1024 + lane * 16;
                l = (uint32_t)c * 1024;
            } else {
                int cc = c - 16, h = cc >> 3, sub = cc & 7;
                g = B8 + (size_t)(bn * 2 + h) * nkt * 8192 + sub * 1024 + lane * 16;
                l = (uint32_t)cc * 1024;
            }
            if (p == 0) { gsrc0 = g; ld0 = l; }
            else if (p == 1) { gsrc1 = g; ld1 = l; }
            else if (p == 2) { gsrc2 = g; ld2 = l; }
            else { gsrc3 = g; ld3 = l; }
        }
    }
    uint8_t* lsbase = isA ? lsA : lsB;

#define ISSUE(GP, LO, KT2, B2)                                                   \
    __builtin_amdgcn_global_load_lds(                                            \
        (const __attribute__((address_space(1))) void*)((GP) + (size_t)(KT2) * 8192), \
        (__attribute__((address_space(3))) void*)(lsbase + (B2) * 16384 + (LO)), \
        16, 0, 0)

    // fragment read bases
    const uint8_t* baseA = lsA + wr * 8192 + hl * 4096 + l31 * 16;
    const uint8_t* baseB = lsB + (wc >> 1) * 8192 + hl * 4096 + (wc & 1) * 1024 + l31 * 16;

    floatx16 acc[4][2];
    #pragma unroll
    for (int m = 0; m < 4; m++)
        #pragma unroll
        for (int n = 0; n < 2; n++)
            acc[m][n] = (floatx16)(0.0f);

#define RD8(BASE, OFF) __builtin_shufflevector(                         \
        *(const intx4*)((BASE) + (OFF)),                                \
        *(const intx4*)((BASE) + (OFF) + 2048), 0, 1, 2, 3, 4, 5, 6, 7)

#define MMX(m, n) acc[m][n] = __builtin_amdgcn_mfma_scale_f32_32x32x64_f8f6f4( \
        af[m], bf[n], acc[m][n], 0, 0, 0, SCL_ONE, 0, SCL_ONE)

    // ---- prologue: stage tiles 0 and 1 ----
    ISSUE(gsrc0, ld0, 0, 0); ISSUE(gsrc1, ld1, 0, 0); ISSUE(gsrc2, ld2, 0, 0); ISSUE(gsrc3, ld3, 0, 0);
    ISSUE(gsrc0, ld0, 1, 1); ISSUE(gsrc1, ld1, 1, 1); ISSUE(gsrc2, ld2, 1, 1); ISSUE(gsrc3, ld3, 1, 1);
    asm volatile("s_waitcnt vmcnt(4)" ::: "memory");
    asm volatile("s_barrier" ::: "memory");

    int cur = 0;
    for (int kt = 0; kt < nkt; kt++) {
        bool pf = (kt + 2 < nkt);
        int ib = cur - 1; if (ib < 0) ib += 3;          // (kt+2) % 3
        const uint8_t* cA = baseA + cur * 16384;
        const uint8_t* cB = baseB + cur * 16384;
        intx8 af[4], bf[2];

        if (pf) { ISSUE(gsrc0, ld0, kt + 2, ib); ISSUE(gsrc1, ld1, kt + 2, ib);
                  ISSUE(gsrc2, ld2, kt + 2, ib); ISSUE(gsrc3, ld3, kt + 2, ib); }

        // all operand reads up front; compiler's partial lgkm waits let early MFMAs
        // overlap late ds_read completions (cross-wave overlap via free-running waves)
        af[0] = RD8(cA, 0);    af[1] = RD8(cA, 512);
        bf[0] = RD8(cB, 0);    bf[1] = RD8(cB, 512);
        af[2] = RD8(cA, 1024); af[3] = RD8(cA, 1536);

        __builtin_amdgcn_s_setprio(1);
        MMX(0, 0); MMX(0, 1); MMX(1, 0); MMX(1, 1);
        MMX(2, 0); MMX(2, 1); MMX(3, 0); MMX(3, 1);
        __builtin_amdgcn_s_setprio(0);

        if (kt + 1 < nkt) {
            if (pf) asm volatile("s_waitcnt vmcnt(4)" ::: "memory");
            else    asm volatile("s_waitcnt vmcnt(0)" ::: "memory");
            asm volatile("s_barrier" ::: "memory");   // buffer kt+1 ready for all waves
        }
        cur++; if (cur == 3) cur = 0;
    }

    float sxv = fmaxf(__uint_as_float(hdr[0]), QEPS) / F8MAX;
    float swv = fmaxf(__uint_as_float(hdr[1]), QEPS) / F8MAX;
    float s = sxv * swv;

    // C/D 32x32: col = lane&31, row = (reg&3) + 8*(reg>>2) + 4*(lane>>5)
    #pragma unroll
    for (int m = 0; m < 4; m++) {
        int row0 = bm * 256 + wr * 128 + m * 32 + 4 * hl;
        #pragma unroll
        for (int n = 0; n < 2; n++) {
            int col = bn * 256 + wc * 64 + n * 32 + l31;
            float bv = bias[col];
            #pragma unroll
            for (int reg = 0; reg < 16; reg++) {
                int row = row0 + (reg & 3) + 8 * (reg >> 2);
                __builtin_nontemporal_store(acc[m][n][reg] * s + bv, &C[(size_t)row * N + col]);
            }
        }
    }
#undef ISSUE
#undef RD8
#undef MMX
}

extern "C" void kernel_launch(void* const* d_in, const int* in_sizes, int n_in,
                              void* d_out, int out_size, void* d_ws, size_t ws_size,
                              hipStream_t stream)
{
    const float* x    = (const float*)d_in[0];
    const float* w    = (const float*)d_in[1];
    const float* bias = (const float*)d_in[2];
    float* out = (float*)d_out;

    int N = in_sizes[2];                 // 1024
    int K = in_sizes[1] / N;             // 1024
    int M = in_sizes[0] / K;             // 65536
    int nx = in_sizes[0];
    int nw = in_sizes[1];
    int nkt = K / 64;                    // 16

    uint8_t* ws = (uint8_t*)d_ws;
    unsigned* hdr = (unsigned*)ws;                    // [0]=amax_x bits, [1]=amax_w bits
    float* px = (float*)(ws + 64);                    // 4096 partials (x)
    float* pw = (float*)(ws + 64 + 16384);            // 4096 partials (w)
    uint8_t* w8 = ws + 65536;
    uint8_t* x8 = ws + 65536 + (size_t)N * K;

    int nhx = (M / 128) * 2;             // 1024 half-panels of x
    int nhw = (N / 128) * 2;             // 16 half-panels of w

    amax_partial_xw<<<AXB, 256, 0, stream>>>(x, nx / 4, w, nw / 4, px, pw);
    quant_fused<<<nhw + nhx, 256, 0, stream>>>(x, w, x8, w8, px, pw, hdr, nhx, nkt, K);

    int nbm = M / 256, nbn = N / 256;
    gemm_fp8_mx<<<nbm * nbn, 512, 0, stream>>>(x8, w8, out, bias, hdr, N, nkt, nbn);
}